// Round 9
// baseline (4330.798 us; speedup 1.0000x reference)
//
#include <hip/hip_runtime.h>
#include <stdint.h>
#include <stddef.h>

// Problem dims
#define B_ 1024
#define S_ 128
#define D_ 256
#define H_ 2048
#define O_ 10
#define V_ 10

// Step-GEMM: C[1024 x 2048] = Hin[1024 x 2048(K)] * W[2048(N) x 2048(K)]^T
//
// Round-9: the untested matrix cell = LOW LDS BYTES x 2 WAVES/SIMD.
// Evidence: r1 (192KB LDS/iter, 2 waves/SIMD) = 17.2 us/step with LDS port
// at 84% -> port-bound. r3/r8 cut LDS bytes but ran 1 wave/SIMD -> latency-
// exposed, same-or-worse. This round: 512 threads (8 waves, 2/SIMD = r1's
// TLP), A direct-from-global into asm double-buffered registers with one
// full K-iter of lead (r8's functionally-proven FIFO), W-only LDS staging
// (3 x 16KB). LDS 80 KB/iter (write 16 + read 64), L2 ~50 KB/iter, MFMA
// 620 cy/SIMD -> overlapped ~1300-1500 cy/iter vs r1's 2700.
// Per-thread FIFO (A:8 + W:2 issues/iter): steady queue
// [A(kt)8, W(kt+1)2, A(kt+1)8, W(kt+2)2]; mid vmcnt: kt0=10, 1..13=12,
// 14=10, 15=0; end vmcnt: <=13 -> 10, 14 -> 8. sched_barrier(0) after
// every wait (rule 18); kt-loop fully unrolled (rule 20).
#define BM 128
#define BN 64
#define BK 128
#define NKT (H_ / BK)                 // 16 K-iterations
#define NSTG 3
#define BSTG (BN * BK)                // 8192 u16 = 16 KB per W stage

typedef unsigned short u16;
typedef short v8s __attribute__((ext_vector_type(8)));    // 8 x bf16 (4 VGPRs)
typedef float v4f __attribute__((ext_vector_type(4)));    // 4 x f32 MFMA C/D
typedef u16 u16x4 __attribute__((ext_vector_type(4)));

__device__ __forceinline__ u16 f2bf(float f) {
  unsigned int u = __float_as_uint(f);
  u += 0x7FFFu + ((u >> 16) & 1u);   // RNE
  return (u16)(u >> 16);
}
__device__ __forceinline__ float bf2f(u16 h) {
  return __uint_as_float(((unsigned int)h) << 16);
}
__device__ __forceinline__ float fast_tanh(float x) {
  float e = __expf(2.0f * x);
  return 1.0f - 2.0f / (e + 1.0f);
}
__device__ __forceinline__ void gl2lds16(const void* g, void* l) {
  __builtin_amdgcn_global_load_lds(
      (const __attribute__((address_space(1))) uint32_t*)g,
      (__attribute__((address_space(3))) uint32_t*)l, 16, 0, 0);
}

// ---------------- Txh[v][h] = b_hx[h] + sum_d embed[v][d]*W_hx[h][d] ----------------
__global__ __launch_bounds__(256) void make_table(const float* __restrict__ embed,
                                                  const float* __restrict__ W_hx,
                                                  const float* __restrict__ b_hx,
                                                  float* __restrict__ Txh) {
  int idx = blockIdx.x * 256 + threadIdx.x;   // 10*2048 = 20480
  int v = idx >> 11, h = idx & 2047;
  const float4* e4 = (const float4*)(embed + v * D_);
  const float4* w4 = (const float4*)(W_hx + (size_t)h * D_);
  float s = b_hx[h];
#pragma unroll 4
  for (int d = 0; d < D_ / 4; ++d) {
    float4 a = e4[d], b = w4[d];
    s = fmaf(a.x, b.x, s); s = fmaf(a.y, b.y, s);
    s = fmaf(a.z, b.z, s); s = fmaf(a.w, b.w, s);
  }
  Txh[idx] = s;
}

// ---------------- W_hh (f32) -> bf16, same [N][K] layout ----------------
__global__ __launch_bounds__(256) void conv_w(const float* __restrict__ W,
                                              u16* __restrict__ Wb) {
  int i = blockIdx.x * 256 + threadIdx.x;
  float4 w = ((const float4*)W)[i];
  u16x4 o = { f2bf(w.x), f2bf(w.y), f2bf(w.z), f2bf(w.w) };
  ((u16x4*)Wb)[i] = o;
}

// ---------------- h0[b][j] = tanh(Txh[x[b,0]][j]) ----------------
__global__ __launch_bounds__(256) void init_h0(const float* __restrict__ Txh,
                                               const int* __restrict__ x,
                                               u16* __restrict__ H0) {
  int idx = blockIdx.x * 256 + threadIdx.x;   // 2M
  int b = idx >> 11, j = idx & 2047;
  int xv = x[b * S_];
  H0[idx] = f2bf(fast_tanh(Txh[xv * H_ + j]));
}

// ---------------- one recurrence step ----------------
// Hout[b][n] = tanh( sum_k Hin[b][k]*Wb[n][k] + Txh[x[b,t]][n] + b_hh[n] )
//
// 8 waves as 4m x 2n: wave w -> rows bm + (w>>1)*32 + [0,32), cols
// bn + (w&1)*32 + [0,32). A-dup between the wc-pair hits L1.
// W LDS tile [64 rows][16 chunks], XOR-swizzled slot(n,c)=c^(n&15); read
// (cc^lane16) with n&15==lane16 -> conflict-free (0 conflicts, all rounds).
// A fragment direct from global: row = bm + wr*32 + i*16 + lane16,
// byte = row*4096 + kt*256 + kc*64 + quad*16 (asm, compiler-proof).
// XCD map (r3-proven): each XCD: 4 bm-groups (2 MB A) x 8 bn-groups
// (2 MB W); W slice step-invariant -> L2-resident.

#define WAITV(N) asm volatile("s_waitcnt vmcnt(" #N ")" ::: "memory")
#define SB0 __builtin_amdgcn_sched_barrier(0)

__global__ __launch_bounds__(512, 1) void rnn_step(const u16* __restrict__ Hin,
                                                   const u16* __restrict__ Wb,
                                                   const float* __restrict__ Txh,
                                                   const int* __restrict__ x,
                                                   const float* __restrict__ b_hh,
                                                   u16* __restrict__ Hout,
                                                   int t) {
  __shared__ __align__(16) u16 Bst[NSTG][BSTG];   // 3 x 16 KB W stages

  const int tid = threadIdx.x;                 // 0..511 (8 waves, 2 per SIMD)
  const int bid = blockIdx.x;
  const int xcd = bid & 7;
  const int sl  = bid >> 3;
  const int xr = xcd >> 2, xc = xcd & 3;
  const int bm = (xr * 4 + (sl >> 3)) * BM;
  const int bn = (xc * 8 + (sl & 7)) * BN;

  const int w = tid >> 6, l = tid & 63;
  const int wr = w >> 1, wc = w & 1;           // wave tile rows wr*32, cols wc*32
  const int lane16 = l & 15, quad = l >> 4;
  const int wbase = w << 6;

  // W staging source offsets (swizzle on global side; proven rounds 0-8)
  unsigned offB[2];
#pragma unroll
  for (int i = 0; i < 2; ++i) {
    int s = i * 512 + tid;
    int n = s >> 4;
    int cg = (s & 15) ^ (n & 15);
    offB[i] = (unsigned)((bn + n) * H_ + cg * 8);
  }
  // A direct-load base byte-offsets, one per m-subtile (i = 0,1)
  unsigned voffA[2];
#pragma unroll
  for (int i = 0; i < 2; ++i)
    voffA[i] = (unsigned)(((bm + wr * 32 + i * 16 + lane16) * H_ + quad * 8) * 2);

  // 2 DMA issues per thread per W stage (1024 slots / 512 threads)
#define STAGE_W(stg, kbase) do {                                            \
    u16* Bs_ = &Bst[stg][0];                                                \
    _Pragma("unroll")                                                       \
    for (int i_ = 0; i_ < 2; ++i_)                                          \
      gl2lds16(Wb + offB[i_] + (kbase), Bs_ + (size_t)(i_ * 512 + wbase) * 8); \
  } while (0)

#define ALD1(DST, VOFF, OFFLIT)                                             \
    asm volatile("global_load_dwordx4 %0, %1, %2 offset:%3"                 \
                 : "=v"(DST)                                                \
                 : "v"(VOFF), "s"(Hin), "n"(OFFLIT)                         \
                 : "memory")

  // issue the 8 A-loads of K-tile kt into set S (kc-major, i inner)
#define ALD8(S, KT) do {                                                    \
    unsigned vk0_ = voffA[0] + (unsigned)((KT) * 256);                      \
    unsigned vk1_ = voffA[1] + (unsigned)((KT) * 256);                      \
    ALD1(ar[S][0], vk0_, 0);   ALD1(ar[S][1], vk1_, 0);                     \
    ALD1(ar[S][2], vk0_, 64);  ALD1(ar[S][3], vk1_, 64);                    \
    ALD1(ar[S][4], vk0_, 128); ALD1(ar[S][5], vk1_, 128);                   \
    ALD1(ar[S][6], vk0_, 192); ALD1(ar[S][7], vk1_, 192);                   \
  } while (0)

#define BSET(BV, KC) do {                                                   \
    const int cc_ = (KC) * 4 + quad;                                        \
    _Pragma("unroll")                                                       \
    for (int j_ = 0; j_ < 2; ++j_) {                                        \
      int n_ = wc * 32 + j_ * 16 + lane16;                                  \
      BV[j_] = *(const v8s*)&Bsb[(size_t)(n_ * 16 + (cc_ ^ lane16)) * 8];   \
    }                                                                       \
  } while (0)

#define MMK(S, KC, BV) do {                                                 \
    _Pragma("unroll")                                                       \
    for (int i_ = 0; i_ < 2; ++i_)                                          \
      _Pragma("unroll")                                                     \
      for (int j_ = 0; j_ < 2; ++j_)                                        \
        acc[i_][j_] = __builtin_amdgcn_mfma_f32_16x16x32_bf16(              \
            ar[S][(KC) * 2 + i_], BV[j_], acc[i_][j_], 0, 0, 0);            \
  } while (0)

  v4f acc[2][2];
#pragma unroll
  for (int i = 0; i < 2; ++i)
#pragma unroll
    for (int j = 0; j < 2; ++j) acc[i][j] = (v4f){0.f, 0.f, 0.f, 0.f};

  v8s ar[2][8];                                // A double-buffer (64 VGPR)

  // prologue: W(0), W(1) staged; A(0) into set 0; land W(0); publish.
  STAGE_W(0, 0);
  STAGE_W(1, BK);
  ALD8(0, 0);
  WAITV(10);            // FIFO [W0 2, W1 2, A0 8] -> drain W0 (newer = 10)
  __builtin_amdgcn_s_barrier();
  asm volatile("" ::: "memory");

#pragma unroll
  for (int kt = 0; kt < NKT; ++kt) {
    const int cs = kt & 1, ps = cs ^ 1;        // static under full unroll

    if (kt + 1 < NKT) ALD8(ps, kt + 1);        // A one full iter ahead
    if (kt + 2 < NKT) STAGE_W((kt + 2) % 3, (kt + 2) * BK);

    const u16* Bsb = &Bst[kt % 3][0];
    v8s bX[2], bY[2];
    BSET(bX, 0);                               // ds_reads start before A-wait
    BSET(bY, 1);

    // mid wait: A(kt) landed (issued one full iter ago).
    // steady FIFO: [A(kt)8, W(kt+1)2, A(kt+1)8, W(kt+2)2] -> newer = 12.
    if (kt == 0)            { WAITV(10); }     // [W1 2, A0 8 | A1 8, W2 2]
    else if (kt < NKT - 2)  { WAITV(12); }
    else if (kt == NKT - 2) { WAITV(10); }     // no W(16): newer = W15 2 + A15 8
    else                    { WAITV(0);  }     // last iter: drain
    SB0;

    MMK(cs, 0, bX);
    BSET(bX, 2);
    MMK(cs, 1, bY);
    BSET(bY, 3);
    MMK(cs, 2, bX);
    MMK(cs, 3, bY);

    if (kt < NKT - 1) {
      // end wait: W(kt+1) landed before publishing barrier.
      if (kt < NKT - 2) { WAITV(10); }         // newer = A(kt+1)8 + W(kt+2)2
      else              { WAITV(8);  }         // kt=14: newer = A(15)8
      // lgkm0: this wave's stage-(kt%3) reads complete before overwrite.
      asm volatile("s_waitcnt lgkmcnt(0)" ::: "memory");
      __builtin_amdgcn_s_barrier();
      asm volatile("" ::: "memory");
    }
  }
#undef STAGE_W
#undef ALD1
#undef ALD8
#undef BSET
#undef MMK

  // epilogue: C/D layout col=lane&15, row=quad*4+reg  [m89-verified]
  float bh[2];
#pragma unroll
  for (int j = 0; j < 2; ++j) bh[j] = b_hh[bn + wc * 32 + j * 16 + lane16];
#pragma unroll
  for (int i = 0; i < 2; ++i) {
#pragma unroll
    for (int r = 0; r < 4; ++r) {
      int row = bm + wr * 32 + i * 16 + quad * 4 + r;
      const float* trow = Txh + x[row * S_ + t] * H_;
      u16* orow = Hout + (size_t)row * H_;
#pragma unroll
      for (int j = 0; j < 2; ++j) {
        int col = bn + wc * 32 + j * 16 + lane16;
        float v = acc[i][j][r] + trow[col] + bh[j];
        orow[col] = f2bf(fast_tanh(v));
      }
    }
  }
}

// ---------------- o = hT @ W_oh^T + b_oh ; softmax over 10 ----------------
__global__ __launch_bounds__(256) void out_softmax(const u16* __restrict__ Hf,
                                                   const float* __restrict__ W_oh,
                                                   const float* __restrict__ b_oh,
                                                   float* __restrict__ out) {
  int b = blockIdx.x, tid = threadIdx.x;
  float hv[8];
  const u16* hr = Hf + (size_t)b * H_ + tid * 8;
#pragma unroll
  for (int u = 0; u < 8; ++u) hv[u] = bf2f(hr[u]);
  float acc[O_];
#pragma unroll
  for (int i = 0; i < O_; ++i) {
    const float* wr = W_oh + (size_t)i * H_ + tid * 8;
    float s = 0.f;
#pragma unroll
    for (int u = 0; u < 8; ++u) s = fmaf(hv[u], wr[u], s);
    acc[i] = s;
  }
#pragma unroll
  for (int off = 32; off > 0; off >>= 1)
#pragma unroll
    for (int i = 0; i < O_; ++i) acc[i] += __shfl_down(acc[i], off);
  __shared__ float red[4][O_];
  if ((tid & 63) == 0)
#pragma unroll
    for (int i = 0; i < O_; ++i) red[tid >> 6][i] = acc[i];
  __syncthreads();
  if (tid == 0) {
    float o[O_], mx = -1e30f;
#pragma unroll
    for (int i = 0; i < O_; ++i) {
      o[i] = red[0][i] + red[1][i] + red[2][i] + red[3][i] + b_oh[i];
      mx = fmaxf(mx, o[i]);
    }
    float se = 0.f;
#pragma unroll
    for (int i = 0; i < O_; ++i) { o[i] = __expf(o[i] - mx); se += o[i]; }
    float inv = 1.f / se;
#pragma unroll
    for (int i = 0; i < O_; ++i) out[b * O_ + i] = o[i] * inv;
  }
}

extern "C" void kernel_launch(void* const* d_in, const int* in_sizes, int n_in,
                              void* d_out, int out_size, void* d_ws, size_t ws_size,
                              hipStream_t stream) {
  const int*   x     = (const int*)  d_in[0];
  const float* embed = (const float*)d_in[1];
  const float* W_hx  = (const float*)d_in[2];
  const float* b_hx  = (const float*)d_in[3];
  const float* W_hh  = (const float*)d_in[4];
  const float* b_hh  = (const float*)d_in[5];
  const float* W_oh  = (const float*)d_in[6];
  const float* b_oh  = (const float*)d_in[7];
  float* out = (float*)d_out;

  // workspace: Txh 80KB | Wb 8MB | Ha 4MB | Hb 4MB  (~16.1 MB)
  char* ws = (char*)d_ws;
  float* Txh = (float*)ws;
  u16* Wb = (u16*)(ws + (80 << 10));
  u16* Ha = (u16*)(ws + (80 << 10) + (8 << 20));
  u16* Hb = (u16*)(ws + (80 << 10) + (12 << 20));

  make_table<<<80, 256, 0, stream>>>(embed, W_hx, b_hx, Txh);
  conv_w<<<4096, 256, 0, stream>>>(W_hh, Wb);
  init_h0<<<8192, 256, 0, stream>>>(Txh, x, Ha);

  for (int t = 1; t < S_; ++t) {
    const u16* hin = (t & 1) ? Ha : Hb;
    u16* hout = (t & 1) ? Hb : Ha;
    rnn_step<<<256, 512, 0, stream>>>(hin, Wb, Txh, x, b_hh, hout, t);
  }
  // t=127 (odd) wrote Hb
  out_softmax<<<B_, 256, 0, stream>>>(Hb, W_oh, b_oh, out);
}